// Round 6
// baseline (276.509 us; speedup 1.0000x reference)
//
#include <hip/hip_runtime.h>

// Problem constants
constexpr int      FRAMES  = 128 * 1024;              // B*T = 131072
constexpr int      FRAME_F = 150;                     // floats per frame
constexpr unsigned NT      = (unsigned)FRAMES * 50u;  // 6,553,600 bone triples
constexpr unsigned NC      = NT / 4u;                 // 1,638,400 chunks of 4 triples
// final = 0.1 * (sum_abs + 0.1*sum_sq) / (FRAMES*150)
constexpr float    SCALE   = 0.1f / ((float)FRAMES * (float)FRAME_F);

constexpr int      BLOCK   = 256;
constexpr int      NBLK    = 2048;                    // partials = 8 KB
constexpr unsigned G       = (unsigned)NBLK * BLOCK;  // 524,288 threads

// One bone term from raw (unmasked) self triple (p,t) and neighbor triple (q,u).
__device__ __forceinline__ float bone_term(
    float p0, float p1, float p2, float t0, float t1, float t2,
    float q0, float q1, float q2, float u0, float u1, float u2)
{
    // masks: targets*mask == targets identically; mask preds only
    const float m0 = (t0 != 0.0f) ? 1.0f : 0.0f;
    const float m1 = (t1 != 0.0f) ? 1.0f : 0.0f;
    const float m2 = (t2 != 0.0f) ? 1.0f : 0.0f;
    const float n0 = (u0 != 0.0f) ? 1.0f : 0.0f;
    const float n1 = (u1 != 0.0f) ? 1.0f : 0.0f;
    const float n2 = (u2 != 0.0f) ? 1.0f : 0.0f;

    const float pm0 = p0 * m0, pm1 = p1 * m1, pm2 = p2 * m2;
    const float qm0 = q0 * n0, qm1 = q1 * n1, qm2 = q2 * n2;

    // L1 term over this triple
    const float ab = fabsf(pm0 - t0) + fabsf(pm1 - t1) + fabsf(pm2 - t2);

    // bone direction term
    const float pd0 = pm0 - qm0, pd1 = pm1 - qm1, pd2 = pm2 - qm2;
    const float td0 = t0 - u0,   td1 = t1 - u1,   td2 = t2 - u2;

    const float pl2 = pd0*pd0 + pd1*pd1 + pd2*pd2;
    const float tl2 = td0*td0 + td1*td1 + td2*td2;
    const float pri = (pl2 > 0.0f) ? __builtin_amdgcn_rsqf(pl2) : 0.0f;
    const float tri = (tl2 > 0.0f) ? __builtin_amdgcn_rsqf(tl2) : 0.0f;

    const float d0 = pd0 * pri - td0 * tri;
    const float d1 = pd1 * pri - td1 * tri;
    const float d2 = pd2 * pri - td2 * tri;
    const float sq = m0*d0*d0 + m1*d1*d1 + m2*d2*d2;  // mask[:, :, :150] re-mask

    return ab + 0.1f * sq;
}

// Per-thread main loop body shared by both kernel variants.
__device__ __forceinline__ float compute_acc(const float* __restrict__ preds,
                                             const float* __restrict__ targets,
                                             unsigned tid, int lane)
{
    float acc = 0.0f;

    #pragma clang loop unroll(disable)
    for (unsigned c = tid; c < NC; c += G) {
        const unsigned bt = c * 4u;                 // base triple, j0 even
        const unsigned j0 = bt % 50u;
        const float* P = preds   + (size_t)bt * 3u; // 16-B aligned
        const float* T = targets + (size_t)bt * 3u;

        const bool w1 = (j0 == 48u);                // k=1 neighbor wraps (j==49)
        const bool w3 = (j0 == 46u);                // k=3 neighbor wraps
        // frame-start triple of the wrapping bone (>= array start; 0 = L1 hit)
        const int woff = w1 ? -144 : (w3 ? -138 : 0);

        // ---- loads: 3x dwordx4 per array + 1 small wrap read ----
        const float4 pa = *reinterpret_cast<const float4*>(P + 0);
        const float4 pb = *reinterpret_cast<const float4*>(P + 4);
        const float4 pc = *reinterpret_cast<const float4*>(P + 8);
        const float4 ta = *reinterpret_cast<const float4*>(T + 0);
        const float4 tb = *reinterpret_cast<const float4*>(T + 4);
        const float4 tc = *reinterpret_cast<const float4*>(T + 8);
        const float pw0 = P[woff+0], pw1 = P[woff+1], pw2 = P[woff+2];
        const float tw0 = T[woff+0], tw1 = T[woff+1], tw2 = T[woff+2];

        // ---- k=3 successor (chunk c+1's first triple) = next lane's pa/ta ----
        // (consecutive lanes own consecutive chunks; active waves are full)
        float sp0 = __shfl_down(pa.x, 1, 64);
        float sp1 = __shfl_down(pa.y, 1, 64);
        float sp2 = __shfl_down(pa.z, 1, 64);
        float st0 = __shfl_down(ta.x, 1, 64);
        float st1 = __shfl_down(ta.y, 1, 64);
        float st2 = __shfl_down(ta.z, 1, 64);
        if (lane == 63 && !w3) {                    // cross-wave fixup (1 lane)
            sp0 = P[12]; sp1 = P[13]; sp2 = P[14];
            st0 = T[12]; st1 = T[13]; st2 = T[14];
        }

        // ---- 4 bone terms; other neighbors are register lane-slides ----
        acc += bone_term(pa.x, pa.y, pa.z,  ta.x, ta.y, ta.z,
                         pa.w, pb.x, pb.y,  ta.w, tb.x, tb.y);            // k=0
        acc += bone_term(pa.w, pb.x, pb.y,  ta.w, tb.x, tb.y,
                         w1 ? pw0 : pb.z, w1 ? pw1 : pb.w, w1 ? pw2 : pc.x,
                         w1 ? tw0 : tb.z, w1 ? tw1 : tb.w, w1 ? tw2 : tc.x); // k=1
        acc += bone_term(pb.z, pb.w, pc.x,  tb.z, tb.w, tc.x,
                         pc.y, pc.z, pc.w,  tc.y, tc.z, tc.w);            // k=2
        acc += bone_term(pc.y, pc.z, pc.w,  tc.y, tc.z, tc.w,
                         w3 ? pw0 : sp0, w3 ? pw1 : sp1, w3 ? pw2 : sp2,
                         w3 ? tw0 : st0, w3 ? tw1 : st1, w3 ? tw2 : st2); // k=3
    }
    return acc;
}

// ---------------- fused single-launch variant ----------------
__global__ __launch_bounds__(BLOCK, 4) void bone_loss_fused(
    const float* __restrict__ preds,
    const float* __restrict__ targets,
    float* __restrict__ partials,
    unsigned* __restrict__ counter,   // zeroed by hipMemsetAsync before launch
    float* __restrict__ out)
{
    const unsigned tid = blockIdx.x * BLOCK + threadIdx.x;
    const int lane = threadIdx.x & 63;

    float acc = compute_acc(preds, targets, tid, lane);

    // ---- block reduction ----
    #pragma unroll
    for (int off = 32; off > 0; off >>= 1)
        acc += __shfl_down(acc, off, 64);

    __shared__ float ws[4];
    __shared__ unsigned sdone;
    const int wid = threadIdx.x >> 6;
    if (lane == 0) ws[wid] = acc;
    __syncthreads();

    if (threadIdx.x == 0) {
        partials[blockIdx.x] = ws[0] + ws[1] + ws[2] + ws[3];
        __threadfence();                              // release partials (device scope)
        const unsigned old = atomicAdd(counter, 1u);  // device-scope by default
        sdone = (old == (unsigned)NBLK - 1u) ? 1u : 0u;
    }
    __syncthreads();

    // last block to finish performs the deterministic final reduction
    if (sdone) {
        __threadfence();                              // acquire: invalidate L1 view
        float v = 0.0f;
        for (int i = threadIdx.x; i < NBLK; i += BLOCK)
            v += partials[i];
        #pragma unroll
        for (int off = 32; off > 0; off >>= 1)
            v += __shfl_down(v, off, 64);
        if (lane == 0) ws[wid] = v;
        __syncthreads();
        if (threadIdx.x == 0)
            out[0] = (ws[0] + ws[1] + ws[2] + ws[3]) * SCALE;
    }
}

// ---------------- fallback two-launch variant ----------------
__global__ __launch_bounds__(BLOCK, 4) void bone_loss_main(
    const float* __restrict__ preds,
    const float* __restrict__ targets,
    float* __restrict__ partials)
{
    const unsigned tid = blockIdx.x * BLOCK + threadIdx.x;
    const int lane = threadIdx.x & 63;
    float acc = compute_acc(preds, targets, tid, lane);

    #pragma unroll
    for (int off = 32; off > 0; off >>= 1)
        acc += __shfl_down(acc, off, 64);

    __shared__ float ws[4];
    const int wid = threadIdx.x >> 6;
    if (lane == 0) ws[wid] = acc;
    __syncthreads();
    if (threadIdx.x == 0)
        partials[blockIdx.x] = ws[0] + ws[1] + ws[2] + ws[3];
}

__global__ __launch_bounds__(256) void bone_loss_finish(
    const float* __restrict__ partials,
    float* __restrict__ out)
{
    float v = 0.0f;
    for (int i = threadIdx.x; i < NBLK; i += 256)
        v += partials[i];

    #pragma unroll
    for (int off = 32; off > 0; off >>= 1)
        v += __shfl_down(v, off, 64);

    __shared__ float ws[4];
    const int wid = threadIdx.x >> 6;
    if ((threadIdx.x & 63) == 0) ws[wid] = v;
    __syncthreads();
    if (threadIdx.x == 0)
        out[0] = (ws[0] + ws[1] + ws[2] + ws[3]) * SCALE;
}

extern "C" void kernel_launch(void* const* d_in, const int* in_sizes, int n_in,
                              void* d_out, int out_size, void* d_ws, size_t ws_size,
                              hipStream_t stream) {
    const float* preds   = (const float*)d_in[0];
    const float* targets = (const float*)d_in[1];
    float* out      = (float*)d_out;
    float* partials = (float*)d_ws;                      // NBLK floats = 8 KB

    if (ws_size >= (size_t)NBLK * 4 + 4) {
        // fused path: counter lives right after partials; zero it each launch
        unsigned* counter = (unsigned*)((char*)d_ws + (size_t)NBLK * 4);
        hipMemsetAsync(counter, 0, 4, stream);
        bone_loss_fused<<<NBLK, BLOCK, 0, stream>>>(preds, targets, partials,
                                                    counter, out);
    } else {
        bone_loss_main<<<NBLK, BLOCK, 0, stream>>>(preds, targets, partials);
        bone_loss_finish<<<1, 256, 0, stream>>>(partials, out);
    }
}

// Round 7
// 175.387 us; speedup vs baseline: 1.5766x; 1.5766x over previous
//
#include <hip/hip_runtime.h>

// Problem constants
constexpr int      FRAMES  = 128 * 1024;              // B*T = 131072
constexpr int      FRAME_F = 150;                     // floats per frame
constexpr unsigned NT      = (unsigned)FRAMES * 50u;  // 6,553,600 bone triples
constexpr unsigned NC      = NT / 4u;                 // 1,638,400 chunks of 4 triples
// final = 0.1 * (sum_abs + 0.1*sum_sq) / (FRAMES*150)
constexpr float    SCALE   = 0.1f / ((float)FRAMES * (float)FRAME_F);

constexpr int      BLOCK   = 256;
constexpr int      NBLK    = 2048;                    // partials = 8 KB (proven)
constexpr unsigned G       = (unsigned)NBLK * BLOCK;  // 524,288 threads; ~3.125 chunks/thread

// One bone term from raw (unmasked) self triple (p,t) and neighbor triple (q,u).
__device__ __forceinline__ float bone_term(
    float p0, float p1, float p2, float t0, float t1, float t2,
    float q0, float q1, float q2, float u0, float u1, float u2)
{
    // masks: targets*mask == targets identically; mask preds only
    const float m0 = (t0 != 0.0f) ? 1.0f : 0.0f;
    const float m1 = (t1 != 0.0f) ? 1.0f : 0.0f;
    const float m2 = (t2 != 0.0f) ? 1.0f : 0.0f;
    const float n0 = (u0 != 0.0f) ? 1.0f : 0.0f;
    const float n1 = (u1 != 0.0f) ? 1.0f : 0.0f;
    const float n2 = (u2 != 0.0f) ? 1.0f : 0.0f;

    const float pm0 = p0 * m0, pm1 = p1 * m1, pm2 = p2 * m2;
    const float qm0 = q0 * n0, qm1 = q1 * n1, qm2 = q2 * n2;

    // L1 term over this triple
    const float ab = fabsf(pm0 - t0) + fabsf(pm1 - t1) + fabsf(pm2 - t2);

    // bone direction term
    const float pd0 = pm0 - qm0, pd1 = pm1 - qm1, pd2 = pm2 - qm2;
    const float td0 = t0 - u0,   td1 = t1 - u1,   td2 = t2 - u2;

    const float pl2 = pd0*pd0 + pd1*pd1 + pd2*pd2;
    const float tl2 = td0*td0 + td1*td1 + td2*td2;
    const float pri = (pl2 > 0.0f) ? __builtin_amdgcn_rsqf(pl2) : 0.0f;
    const float tri = (tl2 > 0.0f) ? __builtin_amdgcn_rsqf(tl2) : 0.0f;

    const float d0 = pd0 * pri - td0 * tri;
    const float d1 = pd1 * pri - td1 * tri;
    const float d2 = pd2 * pri - td2 * tri;
    const float sq = m0*d0*d0 + m1*d1*d1 + m2*d2*d2;  // mask[:, :, :150] re-mask

    return ab + 0.1f * sq;
}

__global__ __launch_bounds__(BLOCK, 4) void bone_loss_main(
    const float* __restrict__ preds,
    const float* __restrict__ targets,
    float* __restrict__ partials)
{
    const unsigned tid = blockIdx.x * BLOCK + threadIdx.x;
    float acc = 0.0f;

    // One 4-triple chunk per iteration; unroll DISABLED so only one chunk's
    // loads are ever live (R2/R3 proved that hoisting multiple chunks' loads
    // into one live range forces scratch spill). TLP (8 waves/SIMD), not ILP,
    // hides latency; within a chunk the 8 dwordx4 + 2 dwordx3 issue back-to-back.
    #pragma clang loop unroll(disable)
    for (unsigned c = tid; c < NC; c += G) {
        const unsigned bt = c * 4u;                 // base triple, j0 = bt%50 even
        const unsigned j0 = bt % 50u;
        const float* P = preds   + (size_t)bt * 3u; // byte 48c, 16-B aligned
        const float* T = targets + (size_t)bt * 3u;

        const bool w1 = (j0 == 48u);                // k=1 neighbor wraps (j==49)
        const bool w3 = (j0 == 46u);                // k=3 neighbor wraps
        // successor chunk-start triple (neighbor of k=3 when no wrap); clamp
        // to own base when w3 (unused there; keeps the final chunk in-bounds)
        const int eoff = w3 ? 0 : 12;
        // frame-start triple of the wrapping bone (always >= array start)
        const int woff = w1 ? -144 : (w3 ? -138 : 0);

        // ---- loads: 4x dwordx4 per array + 1 small wrap read, all named ----
        const float4 pa = *reinterpret_cast<const float4*>(P + 0);
        const float4 pb = *reinterpret_cast<const float4*>(P + 4);
        const float4 pc = *reinterpret_cast<const float4*>(P + 8);
        const float4 ps = *reinterpret_cast<const float4*>(P + eoff);
        const float4 ta = *reinterpret_cast<const float4*>(T + 0);
        const float4 tb = *reinterpret_cast<const float4*>(T + 4);
        const float4 tc = *reinterpret_cast<const float4*>(T + 8);
        const float4 ts = *reinterpret_cast<const float4*>(T + eoff);
        const float pw0 = P[woff+0], pw1 = P[woff+1], pw2 = P[woff+2];
        const float tw0 = T[woff+0], tw1 = T[woff+1], tw2 = T[woff+2];

        // ---- 4 bone terms; neighbors are register lane-slides ----
        acc += bone_term(pa.x, pa.y, pa.z,  ta.x, ta.y, ta.z,
                         pa.w, pb.x, pb.y,  ta.w, tb.x, tb.y);            // k=0
        acc += bone_term(pa.w, pb.x, pb.y,  ta.w, tb.x, tb.y,
                         w1 ? pw0 : pb.z, w1 ? pw1 : pb.w, w1 ? pw2 : pc.x,
                         w1 ? tw0 : tb.z, w1 ? tw1 : tb.w, w1 ? tw2 : tc.x); // k=1
        acc += bone_term(pb.z, pb.w, pc.x,  tb.z, tb.w, tc.x,
                         pc.y, pc.z, pc.w,  tc.y, tc.z, tc.w);            // k=2
        acc += bone_term(pc.y, pc.z, pc.w,  tc.y, tc.z, tc.w,
                         w3 ? pw0 : ps.x, w3 ? pw1 : ps.y, w3 ? pw2 : ps.z,
                         w3 ? tw0 : ts.x, w3 ? tw1 : ts.y, w3 ? tw2 : ts.z); // k=3
    }

    // ---- block reduction ----
    #pragma unroll
    for (int off = 32; off > 0; off >>= 1)
        acc += __shfl_down(acc, off, 64);

    __shared__ float ws[4];
    const int wid = threadIdx.x >> 6;
    if ((threadIdx.x & 63) == 0) ws[wid] = acc;
    __syncthreads();
    if (threadIdx.x == 0)
        partials[blockIdx.x] = ws[0] + ws[1] + ws[2] + ws[3];
}

__global__ __launch_bounds__(256) void bone_loss_finish(
    const float* __restrict__ partials,
    float* __restrict__ out)
{
    float v = 0.0f;
    for (int i = threadIdx.x; i < NBLK; i += 256)
        v += partials[i];

    #pragma unroll
    for (int off = 32; off > 0; off >>= 1)
        v += __shfl_down(v, off, 64);

    __shared__ float ws[4];
    const int wid = threadIdx.x >> 6;
    if ((threadIdx.x & 63) == 0) ws[wid] = v;
    __syncthreads();
    if (threadIdx.x == 0)
        out[0] = (ws[0] + ws[1] + ws[2] + ws[3]) * SCALE;
}

extern "C" void kernel_launch(void* const* d_in, const int* in_sizes, int n_in,
                              void* d_out, int out_size, void* d_ws, size_t ws_size,
                              hipStream_t stream) {
    const float* preds   = (const float*)d_in[0];
    const float* targets = (const float*)d_in[1];
    float* out      = (float*)d_out;
    float* partials = (float*)d_ws;       // NBLK floats = 8 KB

    bone_loss_main<<<NBLK, BLOCK, 0, stream>>>(preds, targets, partials);
    bone_loss_finish<<<1, 256, 0, stream>>>(partials, out);
}